// Round 2
// baseline (565.409 us; speedup 1.0000x reference)
//
#include <hip/hip_runtime.h>
#include <hip/hip_bf16.h>

using bf16 = __hip_bfloat16;
typedef __attribute__((ext_vector_type(8))) __bf16 bf16x8;
typedef __attribute__((ext_vector_type(4))) float floatx4;

#define B_  16
#define T_  1024
#define C_  768
#define M_  16384  // B_*T_

// ---- workspace layout (bytes) ----
// xk/xv/xr/k/v/sr: bf16 M_*C_ = 25165824 each
// WT: 4 * 1179648 (bf16 C_*C_)
// y (fp32, 50331648) aliases xk+xv ; z (bf16) aliases xr
#define OFF_XK ((size_t)0)
#define OFF_XV ((size_t)25165824)
#define OFF_XR ((size_t)50331648)
#define OFF_K  ((size_t)75497472)
#define OFF_V  ((size_t)100663296)
#define OFF_SR ((size_t)125829120)
#define OFF_WT ((size_t)150994944)
#define OFF_Y  ((size_t)0)
#define OFF_Z  ((size_t)50331648)

struct __align__(16) BV8 { bf16 v[8]; };

// ---------------- weight transpose fp32 W[k][n] -> bf16 WT[n][k] ----------------
__global__ __launch_bounds__(256) void transpose_w(
    const float* __restrict__ w0, const float* __restrict__ w1,
    const float* __restrict__ w2, const float* __restrict__ w3,
    bf16* __restrict__ wt) {
  __shared__ float tile[32][33];
  int which = blockIdx.z;
  const float* src = which == 0 ? w0 : which == 1 ? w1 : which == 2 ? w2 : w3;
  bf16* dst = wt + (size_t)which * (C_ * C_);
  int k0 = blockIdx.y * 32;
  int n0 = blockIdx.x * 32;
  int j  = threadIdx.x & 31;
  int i0 = threadIdx.x >> 5;  // 0..7
#pragma unroll
  for (int s = 0; s < 4; s++) {
    int i = i0 + s * 8;
    tile[i][j] = src[(size_t)(k0 + i) * C_ + n0 + j];
  }
  __syncthreads();
#pragma unroll
  for (int s = 0; s < 4; s++) {
    int i = i0 + s * 8;
    dst[(size_t)(n0 + i) * C_ + k0 + j] = __float2bfloat16(tile[j][i]);
  }
}

// ---------------- q_shift + token-mix (fp32 in -> bf16 out) ----------------
__global__ __launch_bounds__(256) void shift_mix(
    const float* __restrict__ x,
    const float* __restrict__ mk, const float* __restrict__ mv, const float* __restrict__ mr,
    bf16* __restrict__ xk, bf16* __restrict__ xv, bf16* __restrict__ xr) {
  int gid = blockIdx.x * 256 + threadIdx.x;   // M_*96 threads, 8 ch each
  int c8 = gid % 96;
  int bt = gid / 96;
  int b  = bt >> 10;
  int t  = bt & 1023;
  int hh = t >> 5, ww = t & 31;
  int c0 = c8 * 8;
  int g  = c8 / 24;        // gamma=0.25 -> 192 ch per group = 24 chunks of 8
  int sh = hh, sw = ww;
  bool valid;
  if (g == 0)      { sw = ww - 1; valid = (ww >= 1);  }
  else if (g == 1) { sw = ww + 1; valid = (ww <= 30); }
  else if (g == 2) { sh = hh - 1; valid = (hh >= 1);  }
  else             { sh = hh + 1; valid = (hh <= 30); }
  size_t off = (size_t)bt * C_ + c0;
  float xs[8], ss[8];
  *(float4*)(xs)     = *(const float4*)(x + off);
  *(float4*)(xs + 4) = *(const float4*)(x + off + 4);
  if (valid) {
    size_t soff = (size_t)(b * 1024 + sh * 32 + sw) * C_ + c0;
    *(float4*)(ss)     = *(const float4*)(x + soff);
    *(float4*)(ss + 4) = *(const float4*)(x + soff + 4);
  } else {
#pragma unroll
    for (int j = 0; j < 8; j++) ss[j] = 0.f;
  }
  BV8 ok, ov, orr;
#pragma unroll
  for (int j = 0; j < 8; j++) {
    float xf = xs[j], sf = ss[j];
    float a  = mk[c0 + j];
    float bm = mv[c0 + j];
    float cm = mr[c0 + j];
    ok.v[j]  = __float2bfloat16(xf * a  + sf * (1.f - a));
    ov.v[j]  = __float2bfloat16(xf * bm + sf * (1.f - bm));
    orr.v[j] = __float2bfloat16(xf * cm + sf * (1.f - cm));
  }
  *(BV8*)(xk + off) = ok;
  *(BV8*)(xv + off) = ov;
  *(BV8*)(xr + off) = orr;
}

// ---------------- bf16 MFMA GEMM: C = A(M,K) @ BT(N,K)^T ----------------
// MODE: 1 = store bf16, 2 = sigmoid -> bf16, 3 = store fp32
template <int MODE>
__global__ __launch_bounds__(256, 2) void gemm_bt(
    const bf16* __restrict__ A, const bf16* __restrict__ BT,
    void* __restrict__ Cout, int M, int N, int K) {
  __shared__ bf16 As[128 * 32];
  __shared__ bf16 Bs[128 * 32];
  int tid  = threadIdx.x;
  int wave = tid >> 6, lane = tid & 63;
  int wm = (wave & 1) * 64, wn = (wave >> 1) * 64;
  size_t m0 = (size_t)blockIdx.y * 128, n0 = (size_t)blockIdx.x * 128;

  floatx4 acc[4][4];
#pragma unroll
  for (int i = 0; i < 4; i++)
#pragma unroll
    for (int j = 0; j < 4; j++) acc[i][j] = (floatx4){0.f, 0.f, 0.f, 0.f};

  int row = tid >> 2;          // 0..63
  int kc  = (tid & 3) * 8;     // k offset (8 bf16 = 16B)
  const bf16* Ab = A  + (m0 + row) * (size_t)K + kc;
  const bf16* Bb = BT + (n0 + row) * (size_t)K + kc;
  bf16* lA = As + tid * 8;
  bf16* lB = Bs + tid * 8;
  int fr  = lane & 15;
  int fko = (lane >> 4) * 8;

  for (int k0 = 0; k0 < K; k0 += 32) {
    __builtin_amdgcn_global_load_lds(
        (const __attribute__((address_space(1))) void*)(Ab + k0),
        (__attribute__((address_space(3))) void*)lA, 16, 0, 0);
    __builtin_amdgcn_global_load_lds(
        (const __attribute__((address_space(1))) void*)(Ab + (size_t)64 * K + k0),
        (__attribute__((address_space(3))) void*)(lA + 2048), 16, 0, 0);
    __builtin_amdgcn_global_load_lds(
        (const __attribute__((address_space(1))) void*)(Bb + k0),
        (__attribute__((address_space(3))) void*)lB, 16, 0, 0);
    __builtin_amdgcn_global_load_lds(
        (const __attribute__((address_space(1))) void*)(Bb + (size_t)64 * K + k0),
        (__attribute__((address_space(3))) void*)(lB + 2048), 16, 0, 0);
    __syncthreads();
    bf16x8 af[4], bfr[4];
#pragma unroll
    for (int mi = 0; mi < 4; mi++)
      af[mi] = *(const bf16x8*)(As + (wm + mi * 16 + fr) * 32 + fko);
#pragma unroll
    for (int ni = 0; ni < 4; ni++)
      bfr[ni] = *(const bf16x8*)(Bs + (wn + ni * 16 + fr) * 32 + fko);
#pragma unroll
    for (int mi = 0; mi < 4; mi++)
#pragma unroll
      for (int ni = 0; ni < 4; ni++)
        acc[mi][ni] = __builtin_amdgcn_mfma_f32_16x16x32_bf16(
            af[mi], bfr[ni], acc[mi][ni], 0, 0, 0);
    __syncthreads();
  }
  // epilogue: C/D layout col=lane&15, row=(lane>>4)*4+i  [m89-verified]
  int cr = (lane >> 4) * 4;
  int cc = lane & 15;
#pragma unroll
  for (int mi = 0; mi < 4; mi++)
#pragma unroll
    for (int ni = 0; ni < 4; ni++)
#pragma unroll
      for (int i = 0; i < 4; i++) {
        size_t r   = m0 + wm + mi * 16 + cr + i;
        size_t col = n0 + wn + ni * 16 + cc;
        float val = acc[mi][ni][i];
        if (MODE == 3) {
          ((float*)Cout)[r * N + col] = val;
        } else {
          if (MODE == 2) val = 1.0f / (1.0f + __expf(-val));
          ((bf16*)Cout)[r * N + col] = __float2bfloat16(val);
        }
      }
}

// ---------------- WKV sequential scan, one thread per (b, c) ----------------
__global__ __launch_bounds__(256) void wkv_kernel(
    const bf16* __restrict__ kk, const bf16* __restrict__ vv,
    const float* __restrict__ sd, const float* __restrict__ sf,
    float* __restrict__ y) {
  int gid = blockIdx.x * 256 + threadIdx.x;  // 12288
  int c = gid % C_, b = gid / C_;
  float w = sd[c] * (1.0f / (float)T_);
  float u = sf[c] * (1.0f / (float)T_);
  const bf16* kp = kk + (size_t)b * (T_ * C_) + c;
  const bf16* vp = vv + (size_t)b * (T_ * C_) + c;
  float* yp = y + (size_t)b * (T_ * C_) + c;
  float p = 0.f, q = 0.f, o = -1e38f;
  float kt = __bfloat162float(kp[0]);
  float vt = __bfloat162float(vp[0]);
  for (int t = 0; t < T_; t++) {
    int tn = (t + 1) & (T_ - 1);  // wrap; last-iter prefetch unused
    float kn = __bfloat162float(kp[(size_t)tn * C_]);
    float vn = __bfloat162float(vp[(size_t)tn * C_]);
    float uk = u + kt;
    float no = fmaxf(o, uk);
    float Af = __expf(o - no);
    float Bf = __expf(uk - no);
    float num = Af * p + Bf * vt;
    float den = Af * q + Bf;
    yp[(size_t)t * C_] = __fdividef(num, den);
    float wo  = w + o;
    float no2 = fmaxf(wo, kt);
    float A2 = __expf(wo - no2);
    float B2 = __expf(kt - no2);
    p = A2 * p + B2 * vt;
    q = A2 * q + B2;
    o = no2;
    kt = kn; vt = vn;
  }
}

// ---------------- LayerNorm(y) * sr -> z (bf16), one block per row ----------------
__global__ __launch_bounds__(256) void ln_sr_kernel(
    const float* __restrict__ y, const bf16* __restrict__ sr,
    const float* __restrict__ gg, const float* __restrict__ bb,
    bf16* __restrict__ z) {
  int rowi = blockIdx.x;
  size_t base = (size_t)rowi * C_;
  int tid = threadIdx.x;
  float v0 = y[base + tid], v1 = y[base + tid + 256], v2 = y[base + tid + 512];
  float s  = v0 + v1 + v2;
  float s2 = v0 * v0 + v1 * v1 + v2 * v2;
#pragma unroll
  for (int off = 32; off > 0; off >>= 1) {
    s  += __shfl_down(s, off);
    s2 += __shfl_down(s2, off);
  }
  __shared__ float red[16];
  int wv = tid >> 6, ln = tid & 63;
  if (ln == 0) { red[wv] = s; red[8 + wv] = s2; }
  __syncthreads();
  if (tid == 0) {
    float ts = red[0] + red[1] + red[2] + red[3];
    float t2 = red[8] + red[9] + red[10] + red[11];
    float mu  = ts * (1.0f / (float)C_);
    float var = t2 * (1.0f / (float)C_) - mu * mu;
    red[0] = mu;
    red[1] = rsqrtf(var + 1e-5f);
  }
  __syncthreads();
  float mu = red[0], rs = red[1];
#pragma unroll
  for (int j = 0; j < 3; j++) {
    int c = tid + j * 256;
    float val = (j == 0 ? v0 : (j == 1 ? v1 : v2));
    float gn  = gg[c];
    float bn  = bb[c];
    float srf = __bfloat162float(sr[base + c]);
    z[base + c] = __float2bfloat16(((val - mu) * rs * gn + bn) * srf);
  }
}

extern "C" void kernel_launch(void* const* d_in, const int* in_sizes, int n_in,
                              void* d_out, int out_size, void* d_ws, size_t ws_size,
                              hipStream_t stream) {
  const float* x  = (const float*)d_in[0];
  const float* sd = (const float*)d_in[3];
  const float* sf = (const float*)d_in[4];
  const float* mk = (const float*)d_in[5];
  const float* mv = (const float*)d_in[6];
  const float* mr = (const float*)d_in[7];
  const float* Wk = (const float*)d_in[8];
  const float* Wv = (const float*)d_in[9];
  const float* Wr = (const float*)d_in[10];
  const float* Wo = (const float*)d_in[11];
  const float* lg = (const float*)d_in[12];
  const float* lb = (const float*)d_in[13];

  char* ws = (char*)d_ws;
  bf16* xk  = (bf16*)(ws + OFF_XK);
  bf16* xv  = (bf16*)(ws + OFF_XV);
  bf16* xr  = (bf16*)(ws + OFF_XR);
  bf16* kb  = (bf16*)(ws + OFF_K);
  bf16* vb  = (bf16*)(ws + OFF_V);
  bf16* srb = (bf16*)(ws + OFF_SR);
  bf16* wt  = (bf16*)(ws + OFF_WT);
  bf16* WkT = wt;
  bf16* WvT = wt + (size_t)C_ * C_;
  bf16* WrT = wt + (size_t)2 * C_ * C_;
  bf16* WoT = wt + (size_t)3 * C_ * C_;
  float* yb = (float*)(ws + OFF_Y);   // aliases xk+xv (free after GEMMs)
  bf16*  zb = (bf16*)(ws + OFF_Z);    // aliases xr

  transpose_w<<<dim3(24, 24, 4), 256, 0, stream>>>(Wk, Wv, Wr, Wo, wt);
  shift_mix<<<(M_ * 96) / 256, 256, 0, stream>>>(x, mk, mv, mr, xk, xv, xr);

  dim3 ggrid(C_ / 128, M_ / 128);
  gemm_bt<1><<<ggrid, 256, 0, stream>>>(xk, WkT, kb, M_, C_, C_);
  gemm_bt<1><<<ggrid, 256, 0, stream>>>(xv, WvT, vb, M_, C_, C_);
  gemm_bt<2><<<ggrid, 256, 0, stream>>>(xr, WrT, srb, M_, C_, C_);

  wkv_kernel<<<(B_ * C_) / 256, 256, 0, stream>>>(kb, vb, sd, sf, yb);
  ln_sr_kernel<<<M_, 256, 0, stream>>>(yb, srb, lg, lb, zb);

  gemm_bt<3><<<ggrid, 256, 0, stream>>>(zb, WoT, (float*)d_out, M_, C_, C_);
}

// Round 3
// 313.479 us; speedup vs baseline: 1.8037x; 1.8037x over previous
//
#include <hip/hip_runtime.h>
#include <hip/hip_bf16.h>

using bf16 = __hip_bfloat16;
typedef __attribute__((ext_vector_type(8))) __bf16 bf16x8;
typedef __attribute__((ext_vector_type(4))) float floatx4;

#define B_  16
#define T_  1024
#define C_  768
#define M_  16384  // B_*T_

// ---- workspace layout (bytes) ----
// xk/xv/xr/kT/vT/sr: bf16 M_*C_ = 25165824 each
// WT: 4 * 1179648 (bf16 C_*C_)
// y (fp32, 50331648) aliases xk+xv ; z (bf16) aliases xr
#define OFF_XK ((size_t)0)
#define OFF_XV ((size_t)25165824)
#define OFF_XR ((size_t)50331648)
#define OFF_K  ((size_t)75497472)
#define OFF_V  ((size_t)100663296)
#define OFF_SR ((size_t)125829120)
#define OFF_WT ((size_t)150994944)
#define OFF_Y  ((size_t)0)
#define OFF_Z  ((size_t)50331648)

struct __align__(16) BV8 { bf16 v[8]; };

// ---------------- weight transpose fp32 W[k][n] -> bf16 WT[n][k] ----------------
__global__ __launch_bounds__(256) void transpose_w(
    const float* __restrict__ w0, const float* __restrict__ w1,
    const float* __restrict__ w2, const float* __restrict__ w3,
    bf16* __restrict__ wt) {
  __shared__ float tile[32][33];
  int which = blockIdx.z;
  const float* src = which == 0 ? w0 : which == 1 ? w1 : which == 2 ? w2 : w3;
  bf16* dst = wt + (size_t)which * (C_ * C_);
  int k0 = blockIdx.y * 32;
  int n0 = blockIdx.x * 32;
  int j  = threadIdx.x & 31;
  int i0 = threadIdx.x >> 5;  // 0..7
#pragma unroll
  for (int s = 0; s < 4; s++) {
    int i = i0 + s * 8;
    tile[i][j] = src[(size_t)(k0 + i) * C_ + n0 + j];
  }
  __syncthreads();
#pragma unroll
  for (int s = 0; s < 4; s++) {
    int i = i0 + s * 8;
    dst[(size_t)(n0 + i) * C_ + k0 + j] = __float2bfloat16(tile[j][i]);
  }
}

// ---------------- q_shift + token-mix (fp32 in -> bf16 out) ----------------
__global__ __launch_bounds__(256) void shift_mix(
    const float* __restrict__ x,
    const float* __restrict__ mk, const float* __restrict__ mv, const float* __restrict__ mr,
    bf16* __restrict__ xk, bf16* __restrict__ xv, bf16* __restrict__ xr) {
  int gid = blockIdx.x * 256 + threadIdx.x;   // M_*96 threads, 8 ch each
  int c8 = gid % 96;
  int bt = gid / 96;
  int b  = bt >> 10;
  int t  = bt & 1023;
  int hh = t >> 5, ww = t & 31;
  int c0 = c8 * 8;
  int g  = c8 / 24;        // gamma=0.25 -> 192 ch per group = 24 chunks of 8
  int sh = hh, sw = ww;
  bool valid;
  if (g == 0)      { sw = ww - 1; valid = (ww >= 1);  }
  else if (g == 1) { sw = ww + 1; valid = (ww <= 30); }
  else if (g == 2) { sh = hh - 1; valid = (hh >= 1);  }
  else             { sh = hh + 1; valid = (hh <= 30); }
  size_t off = (size_t)bt * C_ + c0;
  float xs[8], ss[8];
  *(float4*)(xs)     = *(const float4*)(x + off);
  *(float4*)(xs + 4) = *(const float4*)(x + off + 4);
  if (valid) {
    size_t soff = (size_t)(b * 1024 + sh * 32 + sw) * C_ + c0;
    *(float4*)(ss)     = *(const float4*)(x + soff);
    *(float4*)(ss + 4) = *(const float4*)(x + soff + 4);
  } else {
#pragma unroll
    for (int j = 0; j < 8; j++) ss[j] = 0.f;
  }
  BV8 ok, ov, orr;
#pragma unroll
  for (int j = 0; j < 8; j++) {
    float xf = xs[j], sf = ss[j];
    float a  = mk[c0 + j];
    float bm = mv[c0 + j];
    float cm = mr[c0 + j];
    ok.v[j]  = __float2bfloat16(xf * a  + sf * (1.f - a));
    ov.v[j]  = __float2bfloat16(xf * bm + sf * (1.f - bm));
    orr.v[j] = __float2bfloat16(xf * cm + sf * (1.f - cm));
  }
  *(BV8*)(xk + off) = ok;
  *(BV8*)(xv + off) = ov;
  *(BV8*)(xr + off) = orr;
}

// ---------------- bf16 MFMA GEMM: C = A(M,K) @ BT(N,K)^T ----------------
// MODE: 1 = store bf16, 2 = sigmoid -> bf16, 3 = store fp32
template <int MODE>
__global__ __launch_bounds__(256, 2) void gemm_bt(
    const bf16* __restrict__ A, const bf16* __restrict__ BT,
    void* __restrict__ Cout, int M, int N, int K) {
  __shared__ bf16 As[128 * 32];
  __shared__ bf16 Bs[128 * 32];
  int tid  = threadIdx.x;
  int wave = tid >> 6, lane = tid & 63;
  int wm = (wave & 1) * 64, wn = (wave >> 1) * 64;
  size_t m0 = (size_t)blockIdx.y * 128, n0 = (size_t)blockIdx.x * 128;

  floatx4 acc[4][4];
#pragma unroll
  for (int i = 0; i < 4; i++)
#pragma unroll
    for (int j = 0; j < 4; j++) acc[i][j] = (floatx4){0.f, 0.f, 0.f, 0.f};

  int row = tid >> 2;          // 0..63
  int kc  = (tid & 3) * 8;     // k offset (8 bf16 = 16B)
  const bf16* Ab = A  + (m0 + row) * (size_t)K + kc;
  const bf16* Bb = BT + (n0 + row) * (size_t)K + kc;
  bf16* lA = As + tid * 8;
  bf16* lB = Bs + tid * 8;
  int fr  = lane & 15;
  int fko = (lane >> 4) * 8;

  for (int k0 = 0; k0 < K; k0 += 32) {
    __builtin_amdgcn_global_load_lds(
        (const __attribute__((address_space(1))) void*)(Ab + k0),
        (__attribute__((address_space(3))) void*)lA, 16, 0, 0);
    __builtin_amdgcn_global_load_lds(
        (const __attribute__((address_space(1))) void*)(Ab + (size_t)64 * K + k0),
        (__attribute__((address_space(3))) void*)(lA + 2048), 16, 0, 0);
    __builtin_amdgcn_global_load_lds(
        (const __attribute__((address_space(1))) void*)(Bb + k0),
        (__attribute__((address_space(3))) void*)lB, 16, 0, 0);
    __builtin_amdgcn_global_load_lds(
        (const __attribute__((address_space(1))) void*)(Bb + (size_t)64 * K + k0),
        (__attribute__((address_space(3))) void*)(lB + 2048), 16, 0, 0);
    __syncthreads();
    bf16x8 af[4], bfr[4];
#pragma unroll
    for (int mi = 0; mi < 4; mi++)
      af[mi] = *(const bf16x8*)(As + (wm + mi * 16 + fr) * 32 + fko);
#pragma unroll
    for (int ni = 0; ni < 4; ni++)
      bfr[ni] = *(const bf16x8*)(Bs + (wn + ni * 16 + fr) * 32 + fko);
#pragma unroll
    for (int mi = 0; mi < 4; mi++)
#pragma unroll
      for (int ni = 0; ni < 4; ni++)
        acc[mi][ni] = __builtin_amdgcn_mfma_f32_16x16x32_bf16(
            af[mi], bfr[ni], acc[mi][ni], 0, 0, 0);
    __syncthreads();
  }
  // epilogue: C/D layout col=lane&15, row=(lane>>4)*4+i  [m89-verified]
  int cr = (lane >> 4) * 4;
  int cc = lane & 15;
#pragma unroll
  for (int mi = 0; mi < 4; mi++)
#pragma unroll
    for (int ni = 0; ni < 4; ni++)
#pragma unroll
      for (int i = 0; i < 4; i++) {
        size_t r   = m0 + wm + mi * 16 + cr + i;
        size_t col = n0 + wn + ni * 16 + cc;
        float val = acc[mi][ni][i];
        if (MODE == 3) {
          ((float*)Cout)[r * N + col] = val;
        } else {
          if (MODE == 2) val = 1.0f / (1.0f + __expf(-val));
          ((bf16*)Cout)[r * N + col] = __float2bfloat16(val);
        }
      }
}

// ---------------- WKV chunked scan ----------------
// kT/vT layout: [c][b*1024 + t]  (c-major). 32 segments x 32 steps per (b,c).
// Block: 256 threads = 32 segments x 8 channels, one b per block.
#define SEG 32
#define SL  32
__global__ __launch_bounds__(256) void wkv_chunked(
    const bf16* __restrict__ kT, const bf16* __restrict__ vT,
    const float* __restrict__ sd, const float* __restrict__ sf,
    float* __restrict__ y) {
  int tid = threadIdx.x;
  int s = tid >> 3, cr = tid & 7;
  int b = blockIdx.x / 96, cg = blockIdx.x % 96;
  int c = cg * 8 + cr;
  float w = sd[c] * (1.0f / (float)T_);
  float u = sf[c] * (1.0f / (float)T_);
  size_t base = (size_t)c * M_ + b * T_ + s * SL;
  BV8 kv[4], vv8[4];
#pragma unroll
  for (int j = 0; j < 4; j++) {
    kv[j]  = *(const BV8*)(kT + base + j * 8);
    vv8[j] = *(const BV8*)(vT + base + j * 8);
  }
  // phase 1: per-segment summary from identity state
  float P = 0.f, Q = 0.f, O = -1e38f;
#pragma unroll
  for (int j = 0; j < 4; j++)
#pragma unroll
    for (int i = 0; i < 8; i++) {
      float kt = __bfloat162float(kv[j].v[i]);
      float vt = __bfloat162float(vv8[j].v[i]);
      float wo = w + O;
      float no = fmaxf(wo, kt);
      float A  = __expf(wo - no);
      float Bx = __expf(kt - no);
      P = A * P + Bx * vt;
      Q = A * Q + Bx;
      O = no;
    }
  __shared__ float sP[SEG][8], sQ[SEG][8], sO[SEG][8];
  sP[s][cr] = P; sQ[s][cr] = Q; sO[s][cr] = O;
  __syncthreads();
  // phase 2: exclusive scan across segments (8 threads, one per channel)
  if (s == 0) {
    float p = 0.f, q = 0.f, o = -1e38f;
    float dw = (float)SL * w;
#pragma unroll 1
    for (int t = 0; t < SEG; t++) {
      float Pp = sP[t][cr], Qq = sQ[t][cr], Oo = sO[t][cr];
      sP[t][cr] = p; sQ[t][cr] = q; sO[t][cr] = o;
      float a  = dw + o;
      float no = fmaxf(a, Oo);
      float e1 = __expf(a - no);
      float e2 = __expf(Oo - no);
      p = e1 * p + e2 * Pp;
      q = e1 * q + e2 * Qq;
      o = no;
    }
  }
  __syncthreads();
  float p = sP[s][cr], q = sQ[s][cr], o = sO[s][cr];
  // phase 3: replay segment with true incoming state, emit y [bt][c]
  float* yp = y + ((size_t)(b * T_ + s * SL)) * C_ + c;
#pragma unroll
  for (int j = 0; j < 4; j++)
#pragma unroll
    for (int i = 0; i < 8; i++) {
      float kt = __bfloat162float(kv[j].v[i]);
      float vt = __bfloat162float(vv8[j].v[i]);
      float uk = u + kt;
      float no = fmaxf(o, uk);
      float A  = __expf(o - no);
      float Bx = __expf(uk - no);
      yp[(size_t)(j * 8 + i) * C_] = __fdividef(A * p + Bx * vt, A * q + Bx);
      float wo  = w + o;
      float no2 = fmaxf(wo, kt);
      float A2 = __expf(wo - no2);
      float B2 = __expf(kt - no2);
      p = A2 * p + B2 * vt;
      q = A2 * q + B2;
      o = no2;
    }
}

// ---------------- LayerNorm(y) * sr -> z (bf16), one block per row ----------------
__global__ __launch_bounds__(256) void ln_sr_kernel(
    const float* __restrict__ y, const bf16* __restrict__ sr,
    const float* __restrict__ gg, const float* __restrict__ bb,
    bf16* __restrict__ z) {
  int rowi = blockIdx.x;
  size_t base = (size_t)rowi * C_;
  int tid = threadIdx.x;
  float v0 = y[base + tid], v1 = y[base + tid + 256], v2 = y[base + tid + 512];
  float s  = v0 + v1 + v2;
  float s2 = v0 * v0 + v1 * v1 + v2 * v2;
#pragma unroll
  for (int off = 32; off > 0; off >>= 1) {
    s  += __shfl_down(s, off);
    s2 += __shfl_down(s2, off);
  }
  __shared__ float red[16];
  int wv = tid >> 6, ln = tid & 63;
  if (ln == 0) { red[wv] = s; red[8 + wv] = s2; }
  __syncthreads();
  if (tid == 0) {
    float ts = red[0] + red[1] + red[2] + red[3];
    float t2 = red[8] + red[9] + red[10] + red[11];
    float mu  = ts * (1.0f / (float)C_);
    float var = t2 * (1.0f / (float)C_) - mu * mu;
    red[0] = mu;
    red[1] = rsqrtf(var + 1e-5f);
  }
  __syncthreads();
  float mu = red[0], rs = red[1];
#pragma unroll
  for (int j = 0; j < 3; j++) {
    int c = tid + j * 256;
    float val = (j == 0 ? v0 : (j == 1 ? v1 : v2));
    float gn  = gg[c];
    float bn  = bb[c];
    float srf = __bfloat162float(sr[base + c]);
    z[base + c] = __float2bfloat16(((val - mu) * rs * gn + bn) * srf);
  }
}

extern "C" void kernel_launch(void* const* d_in, const int* in_sizes, int n_in,
                              void* d_out, int out_size, void* d_ws, size_t ws_size,
                              hipStream_t stream) {
  const float* x  = (const float*)d_in[0];
  const float* sd = (const float*)d_in[3];
  const float* sf = (const float*)d_in[4];
  const float* mk = (const float*)d_in[5];
  const float* mv = (const float*)d_in[6];
  const float* mr = (const float*)d_in[7];
  const float* Wk = (const float*)d_in[8];
  const float* Wv = (const float*)d_in[9];
  const float* Wr = (const float*)d_in[10];
  const float* Wo = (const float*)d_in[11];
  const float* lg = (const float*)d_in[12];
  const float* lb = (const float*)d_in[13];

  char* ws = (char*)d_ws;
  bf16* xk  = (bf16*)(ws + OFF_XK);
  bf16* xv  = (bf16*)(ws + OFF_XV);
  bf16* xr  = (bf16*)(ws + OFF_XR);
  bf16* kTb = (bf16*)(ws + OFF_K);
  bf16* vTb = (bf16*)(ws + OFF_V);
  bf16* srb = (bf16*)(ws + OFF_SR);
  bf16* wt  = (bf16*)(ws + OFF_WT);
  bf16* WkT = wt;
  bf16* WvT = wt + (size_t)C_ * C_;
  bf16* WrT = wt + (size_t)2 * C_ * C_;
  bf16* WoT = wt + (size_t)3 * C_ * C_;
  float* yb = (float*)(ws + OFF_Y);   // aliases xk+xv (free after GEMMs)
  bf16*  zb = (bf16*)(ws + OFF_Z);    // aliases xr

  transpose_w<<<dim3(24, 24, 4), 256, 0, stream>>>(Wk, Wv, Wr, Wo, wt);
  shift_mix<<<(M_ * 96) / 256, 256, 0, stream>>>(x, mk, mv, mr, xk, xv, xr);

  // k^T, v^T in [c][bt] layout: C'[c][bt] = sum_j WkT[c][j] * xk[bt][j]
  dim3 tgrid(M_ / 128, C_ / 128);
  gemm_bt<1><<<tgrid, 256, 0, stream>>>(WkT, xk, kTb, C_, M_, C_);
  gemm_bt<1><<<tgrid, 256, 0, stream>>>(WvT, xv, vTb, C_, M_, C_);
  // sr stays [bt][c]
  dim3 ggrid(C_ / 128, M_ / 128);
  gemm_bt<2><<<ggrid, 256, 0, stream>>>(xr, WrT, srb, M_, C_, C_);

  wkv_chunked<<<B_ * 96, 256, 0, stream>>>(kTb, vTb, sd, sf, yb);
  ln_sr_kernel<<<M_, 256, 0, stream>>>(yb, srb, lg, lb, zb);

  gemm_bt<3><<<ggrid, 256, 0, stream>>>(zb, WoT, (float*)d_out, M_, C_, C_);
}

// Round 4
// 305.682 us; speedup vs baseline: 1.8497x; 1.0255x over previous
//
#include <hip/hip_runtime.h>
#include <hip/hip_bf16.h>

using bf16 = __hip_bfloat16;
typedef __attribute__((ext_vector_type(8))) __bf16 bf16x8;
typedef __attribute__((ext_vector_type(4))) float floatx4;

#define B_  16
#define T_  1024
#define C_  768
#define M_  16384  // B_*T_

#define OFF_XK ((size_t)0)
#define OFF_XV ((size_t)25165824)
#define OFF_XR ((size_t)50331648)
#define OFF_K  ((size_t)75497472)
#define OFF_V  ((size_t)100663296)
#define OFF_SR ((size_t)125829120)
#define OFF_WT ((size_t)150994944)
#define OFF_Y  ((size_t)0)          // bf16 y aliases xk (dead after GEMMs)
#define OFF_Z  ((size_t)50331648)   // bf16 z aliases xr (dead after sr GEMM)

struct __align__(16) BV8 { bf16 v[8]; };

// ---------------- weight transpose fp32 W[k][n] -> bf16 WT[n][k] ----------------
__global__ __launch_bounds__(256) void transpose_w(
    const float* __restrict__ w0, const float* __restrict__ w1,
    const float* __restrict__ w2, const float* __restrict__ w3,
    bf16* __restrict__ wt) {
  __shared__ float tile[32][33];
  int which = blockIdx.z;
  const float* src = which == 0 ? w0 : which == 1 ? w1 : which == 2 ? w2 : w3;
  bf16* dst = wt + (size_t)which * (C_ * C_);
  int k0 = blockIdx.y * 32;
  int n0 = blockIdx.x * 32;
  int j  = threadIdx.x & 31;
  int i0 = threadIdx.x >> 5;
#pragma unroll
  for (int s = 0; s < 4; s++) {
    int i = i0 + s * 8;
    tile[i][j] = src[(size_t)(k0 + i) * C_ + n0 + j];
  }
  __syncthreads();
#pragma unroll
  for (int s = 0; s < 4; s++) {
    int i = i0 + s * 8;
    dst[(size_t)(n0 + i) * C_ + k0 + j] = __float2bfloat16(tile[j][i]);
  }
}

// ---------------- q_shift + token-mix (fp32 in -> bf16 out) ----------------
__global__ __launch_bounds__(256) void shift_mix(
    const float* __restrict__ x,
    const float* __restrict__ mk, const float* __restrict__ mv, const float* __restrict__ mr,
    bf16* __restrict__ xk, bf16* __restrict__ xv, bf16* __restrict__ xr) {
  int gid = blockIdx.x * 256 + threadIdx.x;
  int c8 = gid % 96;
  int bt = gid / 96;
  int b  = bt >> 10;
  int t  = bt & 1023;
  int hh = t >> 5, ww = t & 31;
  int c0 = c8 * 8;
  int g  = c8 / 24;
  int sh = hh, sw = ww;
  bool valid;
  if (g == 0)      { sw = ww - 1; valid = (ww >= 1);  }
  else if (g == 1) { sw = ww + 1; valid = (ww <= 30); }
  else if (g == 2) { sh = hh - 1; valid = (hh >= 1);  }
  else             { sh = hh + 1; valid = (hh <= 30); }
  size_t off = (size_t)bt * C_ + c0;
  float xs[8], ss[8];
  *(float4*)(xs)     = *(const float4*)(x + off);
  *(float4*)(xs + 4) = *(const float4*)(x + off + 4);
  if (valid) {
    size_t soff = (size_t)(b * 1024 + sh * 32 + sw) * C_ + c0;
    *(float4*)(ss)     = *(const float4*)(x + soff);
    *(float4*)(ss + 4) = *(const float4*)(x + soff + 4);
  } else {
#pragma unroll
    for (int j = 0; j < 8; j++) ss[j] = 0.f;
  }
  BV8 ok, ov, orr;
#pragma unroll
  for (int j = 0; j < 8; j++) {
    float xf = xs[j], sf = ss[j];
    float a  = mk[c0 + j];
    float bm = mv[c0 + j];
    float cm = mr[c0 + j];
    ok.v[j]  = __float2bfloat16(xf * a  + sf * (1.f - a));
    ov.v[j]  = __float2bfloat16(xf * bm + sf * (1.f - bm));
    orr.v[j] = __float2bfloat16(xf * cm + sf * (1.f - cm));
  }
  *(BV8*)(xk + off) = ok;
  *(BV8*)(xv + off) = ov;
  *(BV8*)(xr + off) = orr;
}

// ---- shared GEMM body: 128x128 tile, BK=64 as two BK=32 panels ----
// LDS panel layout: [half][row 0..127][32 k], stride 32 elems (m97-proven, conflict-free)
// Staging chunk i of thread t -> LDS element t*8 + i*2048 (wave-uniform linear for glds):
//   row = ((t>>2) + i*64) & 127, kk = (t&3)*8 + (i>>1)*32
template <int MODE>
__device__ __forceinline__ void gemm_body(
    const bf16* __restrict__ A, const bf16* __restrict__ BT,
    void* __restrict__ Cout, int M, int N, int K,
    int bx, int by) {
  __shared__ bf16 As[128 * 64];
  __shared__ bf16 Bs[128 * 64];
  int tid  = threadIdx.x;
  int wave = tid >> 6, lane = tid & 63;
  int wm = (wave & 1) * 64, wn = (wave >> 1) * 64;
  size_t m0 = (size_t)by * 128, n0 = (size_t)bx * 128;

  floatx4 acc[4][4];
#pragma unroll
  for (int i = 0; i < 4; i++)
#pragma unroll
    for (int j = 0; j < 4; j++) acc[i][j] = (floatx4){0.f, 0.f, 0.f, 0.f};

  // per-chunk global source coords
  int srow[4], skk[4];
#pragma unroll
  for (int i = 0; i < 4; i++) {
    srow[i] = ((tid >> 2) + i * 64) & 127;
    skk[i]  = (tid & 3) * 8 + (i >> 1) * 32;
  }
  bf16* lA = As + tid * 8;
  bf16* lB = Bs + tid * 8;
  int fr  = lane & 15;
  int fko = (lane >> 4) * 8;

  for (int k0 = 0; k0 < K; k0 += 64) {
#pragma unroll
    for (int i = 0; i < 4; i++) {
      __builtin_amdgcn_global_load_lds(
          (const __attribute__((address_space(1))) void*)(A + (m0 + srow[i]) * (size_t)K + k0 + skk[i]),
          (__attribute__((address_space(3))) void*)(lA + i * 2048), 16, 0, 0);
      __builtin_amdgcn_global_load_lds(
          (const __attribute__((address_space(1))) void*)(BT + (n0 + srow[i]) * (size_t)K + k0 + skk[i]),
          (__attribute__((address_space(3))) void*)(lB + i * 2048), 16, 0, 0);
    }
    __syncthreads();
#pragma unroll
    for (int s = 0; s < 2; s++) {
      bf16x8 af[4], bfr[4];
#pragma unroll
      for (int mi = 0; mi < 4; mi++)
        af[mi] = *(const bf16x8*)(As + s * 4096 + (wm + mi * 16 + fr) * 32 + fko);
#pragma unroll
      for (int ni = 0; ni < 4; ni++)
        bfr[ni] = *(const bf16x8*)(Bs + s * 4096 + (wn + ni * 16 + fr) * 32 + fko);
#pragma unroll
      for (int mi = 0; mi < 4; mi++)
#pragma unroll
        for (int ni = 0; ni < 4; ni++)
          acc[mi][ni] = __builtin_amdgcn_mfma_f32_16x16x32_bf16(
              af[mi], bfr[ni], acc[mi][ni], 0, 0, 0);
    }
    __syncthreads();
  }
  int cr = (lane >> 4) * 4;
  int cc = lane & 15;
#pragma unroll
  for (int mi = 0; mi < 4; mi++)
#pragma unroll
    for (int ni = 0; ni < 4; ni++)
#pragma unroll
      for (int i = 0; i < 4; i++) {
        size_t r   = m0 + wm + mi * 16 + cr + i;
        size_t col = n0 + wn + ni * 16 + cc;
        float val = acc[mi][ni][i];
        if (MODE == 3) {
          ((float*)Cout)[r * N + col] = val;
        } else {
          if (MODE == 2) val = 1.0f / (1.0f + __expf(-val));
          ((bf16*)Cout)[r * N + col] = __float2bfloat16(val);
        }
      }
}

template <int MODE>
__global__ __launch_bounds__(256, 2) void gemm_bt(
    const bf16* __restrict__ A, const bf16* __restrict__ BT,
    void* __restrict__ Cout, int M, int N, int K) {
  gemm_body<MODE>(A, BT, Cout, M, N, K, blockIdx.x, blockIdx.y);
}

// merged k^T / v^T GEMM: blockIdx.z selects operand set
__global__ __launch_bounds__(256, 2) void gemm_kv(
    const bf16* __restrict__ A0, const bf16* __restrict__ B0, bf16* __restrict__ C0,
    const bf16* __restrict__ A1, const bf16* __restrict__ B1, bf16* __restrict__ C1,
    int M, int N, int K) {
  if (blockIdx.z == 0)
    gemm_body<1>(A0, B0, C0, M, N, K, blockIdx.x, blockIdx.y);
  else
    gemm_body<1>(A1, B1, C1, M, N, K, blockIdx.x, blockIdx.y);
}

// ---------------- WKV chunked scan (y out bf16) ----------------
#define SEG 32
#define SL  32
__global__ __launch_bounds__(256) void wkv_chunked(
    const bf16* __restrict__ kT, const bf16* __restrict__ vT,
    const float* __restrict__ sd, const float* __restrict__ sf,
    bf16* __restrict__ y) {
  int tid = threadIdx.x;
  int s = tid >> 3, cr = tid & 7;
  int b = blockIdx.x / 96, cg = blockIdx.x % 96;
  int c = cg * 8 + cr;
  float w = sd[c] * (1.0f / (float)T_);
  float u = sf[c] * (1.0f / (float)T_);
  size_t base = (size_t)c * M_ + b * T_ + s * SL;
  BV8 kv[4], vv8[4];
#pragma unroll
  for (int j = 0; j < 4; j++) {
    kv[j]  = *(const BV8*)(kT + base + j * 8);
    vv8[j] = *(const BV8*)(vT + base + j * 8);
  }
  float P = 0.f, Q = 0.f, O = -1e38f;
#pragma unroll
  for (int j = 0; j < 4; j++)
#pragma unroll
    for (int i = 0; i < 8; i++) {
      float kt = __bfloat162float(kv[j].v[i]);
      float vt = __bfloat162float(vv8[j].v[i]);
      float wo = w + O;
      float no = fmaxf(wo, kt);
      float A  = __expf(wo - no);
      float Bx = __expf(kt - no);
      P = A * P + Bx * vt;
      Q = A * Q + Bx;
      O = no;
    }
  __shared__ float sP[SEG][8], sQ[SEG][8], sO[SEG][8];
  sP[s][cr] = P; sQ[s][cr] = Q; sO[s][cr] = O;
  __syncthreads();
  if (s == 0) {
    float p = 0.f, q = 0.f, o = -1e38f;
    float dw = (float)SL * w;
#pragma unroll 1
    for (int t = 0; t < SEG; t++) {
      float Pp = sP[t][cr], Qq = sQ[t][cr], Oo = sO[t][cr];
      sP[t][cr] = p; sQ[t][cr] = q; sO[t][cr] = o;
      float a  = dw + o;
      float no = fmaxf(a, Oo);
      float e1 = __expf(a - no);
      float e2 = __expf(Oo - no);
      p = e1 * p + e2 * Pp;
      q = e1 * q + e2 * Qq;
      o = no;
    }
  }
  __syncthreads();
  float p = sP[s][cr], q = sQ[s][cr], o = sO[s][cr];
  bf16* yp = y + ((size_t)(b * T_ + s * SL)) * C_ + c;
#pragma unroll
  for (int j = 0; j < 4; j++)
#pragma unroll
    for (int i = 0; i < 8; i++) {
      float kt = __bfloat162float(kv[j].v[i]);
      float vt = __bfloat162float(vv8[j].v[i]);
      float uk = u + kt;
      float no = fmaxf(o, uk);
      float A  = __expf(o - no);
      float Bx = __expf(uk - no);
      yp[(size_t)(j * 8 + i) * C_] =
          __float2bfloat16(__fdividef(A * p + Bx * vt, A * q + Bx));
      float wo  = w + o;
      float no2 = fmaxf(wo, kt);
      float A2 = __expf(wo - no2);
      float B2 = __expf(kt - no2);
      p = A2 * p + B2 * vt;
      q = A2 * q + B2;
      o = no2;
    }
}

// ---------------- LayerNorm(y)*sr -> z (bf16) ----------------
__global__ __launch_bounds__(256) void ln_sr_kernel(
    const bf16* __restrict__ y, const bf16* __restrict__ sr,
    const float* __restrict__ gg, const float* __restrict__ bb,
    bf16* __restrict__ z) {
  int rowi = blockIdx.x;
  size_t base = (size_t)rowi * C_;
  int tid = threadIdx.x;
  float v0 = __bfloat162float(y[base + tid]);
  float v1 = __bfloat162float(y[base + tid + 256]);
  float v2 = __bfloat162float(y[base + tid + 512]);
  float s  = v0 + v1 + v2;
  float s2 = v0 * v0 + v1 * v1 + v2 * v2;
#pragma unroll
  for (int off = 32; off > 0; off >>= 1) {
    s  += __shfl_down(s, off);
    s2 += __shfl_down(s2, off);
  }
  __shared__ float red[16];
  int wv = tid >> 6, ln = tid & 63;
  if (ln == 0) { red[wv] = s; red[8 + wv] = s2; }
  __syncthreads();
  if (tid == 0) {
    float ts = red[0] + red[1] + red[2] + red[3];
    float t2 = red[8] + red[9] + red[10] + red[11];
    float mu  = ts * (1.0f / (float)C_);
    float var = t2 * (1.0f / (float)C_) - mu * mu;
    red[0] = mu;
    red[1] = rsqrtf(var + 1e-5f);
  }
  __syncthreads();
  float mu = red[0], rs = red[1];
#pragma unroll
  for (int j = 0; j < 3; j++) {
    int c = tid + j * 256;
    float val = (j == 0 ? v0 : (j == 1 ? v1 : v2));
    float gn  = gg[c];
    float bn  = bb[c];
    float srf = __bfloat162float(sr[base + c]);
    z[base + c] = __float2bfloat16(((val - mu) * rs * gn + bn) * srf);
  }
}

extern "C" void kernel_launch(void* const* d_in, const int* in_sizes, int n_in,
                              void* d_out, int out_size, void* d_ws, size_t ws_size,
                              hipStream_t stream) {
  const float* x  = (const float*)d_in[0];
  const float* sd = (const float*)d_in[3];
  const float* sf = (const float*)d_in[4];
  const float* mk = (const float*)d_in[5];
  const float* mv = (const float*)d_in[6];
  const float* mr = (const float*)d_in[7];
  const float* Wk = (const float*)d_in[8];
  const float* Wv = (const float*)d_in[9];
  const float* Wr = (const float*)d_in[10];
  const float* Wo = (const float*)d_in[11];
  const float* lg = (const float*)d_in[12];
  const float* lb = (const float*)d_in[13];

  char* ws = (char*)d_ws;
  bf16* xk  = (bf16*)(ws + OFF_XK);
  bf16* xv  = (bf16*)(ws + OFF_XV);
  bf16* xr  = (bf16*)(ws + OFF_XR);
  bf16* kTb = (bf16*)(ws + OFF_K);
  bf16* vTb = (bf16*)(ws + OFF_V);
  bf16* srb = (bf16*)(ws + OFF_SR);
  bf16* wt  = (bf16*)(ws + OFF_WT);
  bf16* WkT = wt;
  bf16* WvT = wt + (size_t)C_ * C_;
  bf16* WrT = wt + (size_t)2 * C_ * C_;
  bf16* WoT = wt + (size_t)3 * C_ * C_;
  bf16* yb  = (bf16*)(ws + OFF_Y);
  bf16* zb  = (bf16*)(ws + OFF_Z);

  transpose_w<<<dim3(24, 24, 4), 256, 0, stream>>>(Wk, Wv, Wr, Wo, wt);
  shift_mix<<<(M_ * 96) / 256, 256, 0, stream>>>(x, mk, mv, mr, xk, xv, xr);

  // k^T, v^T in [c][bt] layout (merged launch)
  gemm_kv<<<dim3(M_ / 128, C_ / 128, 2), 256, 0, stream>>>(
      WkT, xk, kTb, WvT, xv, vTb, C_, M_, C_);
  // sr stays [bt][c]
  dim3 ggrid(C_ / 128, M_ / 128);
  gemm_bt<2><<<ggrid, 256, 0, stream>>>(xr, WrT, srb, M_, C_, C_);

  wkv_chunked<<<B_ * 96, 256, 0, stream>>>(kTb, vTb, sd, sf, yb);
  ln_sr_kernel<<<M_, 256, 0, stream>>>(yb, srb, lg, lb, zb);

  gemm_bt<3><<<ggrid, 256, 0, stream>>>(zb, WoT, (float*)d_out, M_, C_, C_);
}